// Round 15
// baseline (13422.884 us; speedup 1.0000x reference)
//
#include <hip/hip_runtime.h>

#define BB 32
#define SS 64
#define TT 64
#define VV 32000
#define EE 512
#define HH 1024
#define GRID 512
#define BLK 512
#define NFC 500          // FC tiles of 64 j
#define ASTR 16          // barrier slot stride in ints (64B)
#define XSTR 264         // FC x double-chunk row stride (256 + 8 pad)
#define FLTMAX 3.402823466e38f

typedef unsigned long long u64;

struct Par {
  const int *src, *tgt, *tmask;
  const float *enc_embed, *dec_embed;
  const float *enc_wih0, *enc_whh0, *enc_b0;
  const float *enc_wih1, *enc_whh1, *enc_b1;
  const float *dec_wih0, *dec_whh0, *dec_b0;
  const float *dec_wih1, *dec_whh1, *dec_b1;
  const float *fc_w, *fc_b;
  float *out;
  float *hA0, *hA1;               // layer-0 h double buffer (coherent)
  float *hBall;                   // 64 slots x [32][1024] h-history (coherent)
  float *cA, *cB;                 // block-private cell state
  float2 *cand;                   // [500][32]
  int *tok;                       // [32]
  int *arr; int *gen;
};

__device__ __forceinline__ float sigf(float x) { return 1.0f / (1.0f + expf(-x)); }

// ---- coherent agent-scope RELAXED access (no L2-invalidate fences) --------
__device__ __forceinline__ float2 ldc2(const float* p) {
  u64 v = __hip_atomic_load((const u64*)p, __ATOMIC_RELAXED, __HIP_MEMORY_SCOPE_AGENT);
  union { u64 u; float2 f; } c; c.u = v; return c.f;
}
__device__ __forceinline__ void stc2(float* p, float x, float y) {
  union { u64 u; float2 f; } c; c.f = make_float2(x, y);
  __hip_atomic_store((u64*)p, c.u, __ATOMIC_RELAXED, __HIP_MEMORY_SCOPE_AGENT);
}
__device__ __forceinline__ void stc1(float* p, float x) {
  __hip_atomic_store(p, x, __ATOMIC_RELAXED, __HIP_MEMORY_SCOPE_AGENT);
}
__device__ __forceinline__ int ldci(const int* p) {
  return __hip_atomic_load(p, __ATOMIC_RELAXED, __HIP_MEMORY_SCOPE_AGENT);
}

// ---------------------------------------------------------------------------
// Fence-free grid barrier: 64B-stride arrival slots, 16 replicated gen lines,
// exponential-backoff polling. REQUIRES all 512 blocks co-resident.
// ---------------------------------------------------------------------------
__device__ __forceinline__ void gbar(int* arr, int* gen, int target) {
  __syncthreads();
  asm volatile("s_waitcnt vmcnt(0)" ::: "memory");
  if (blockIdx.x == 0) {
    if (threadIdx.x < 64) {
      const int s = threadIdx.x;
      int spin = 0;
      for (;;) {
        bool ok = true;
#pragma unroll
        for (int o = 0; o < GRID; o += 64) {
          int idx = s + o;
          int a = (idx == 0) ? target
              : __hip_atomic_load(arr + idx * ASTR, __ATOMIC_RELAXED, __HIP_MEMORY_SCOPE_AGENT);
          ok &= (a >= target);
        }
        if (__all(ok)) break;
        if (spin < 8) __builtin_amdgcn_s_sleep(1);
        else          __builtin_amdgcn_s_sleep(8);
        ++spin;
      }
    }
    __syncthreads();
    if (threadIdx.x < 16)
      __hip_atomic_store(gen + threadIdx.x * ASTR, target, __ATOMIC_RELAXED, __HIP_MEMORY_SCOPE_AGENT);
  } else {
    if (threadIdx.x == 0) {
      __hip_atomic_store(arr + blockIdx.x * ASTR, target, __ATOMIC_RELAXED, __HIP_MEMORY_SCOPE_AGENT);
      int spin = 0;
      while (__hip_atomic_load(gen + (blockIdx.x & 15) * ASTR, __ATOMIC_RELAXED, __HIP_MEMORY_SCOPE_AGENT) < target) {
        if (spin < 4)       __builtin_amdgcn_s_sleep(1);
        else if (spin < 16) __builtin_amdgcn_s_sleep(8);
        else                __builtin_amdgcn_s_sleep(32);
        ++spin;
      }
    }
    __syncthreads();
  }
  asm volatile("" ::: "memory");
}

// ---------------------------------------------------------------------------
// LSTM partial accumulate (u-tile 4 -> 16 gate rows, acc[16]); weights staged
// via LDS (coalesced 1KB/instr), read back as 2-way-broadcast b128 (free).
// Threads: b = tid&31, tc = tid>>5 (16 k-slices of 16 per 256-chunk).
// ---------------------------------------------------------------------------
__device__ __forceinline__ void lstm_accum(
    const float* __restrict__ tab, const int* __restrict__ stokL,
    const float* __restrict__ xcoh, int lenx,
    const float* __restrict__ W, int u0,
    float* __restrict__ acc, float* __restrict__ wbuf)
{
  const int tid = threadIdx.x;
  const int b = tid & 31, tc = tid >> 5;
  const int lane = tid & 63, wid = tid >> 6;
  const int r2 = wid + 8;
  const float* wr1 = W + (size_t)((wid >> 2) * HH + u0 + (wid & 3)) * lenx + (lane << 2);
  const float* wr2 = W + (size_t)((r2  >> 2) * HH + u0 + (r2  & 3)) * lenx + (lane << 2);
  const int ncx = lenx >> 8;
  for (int c = 0; c < ncx; ++c) {
    const int col = c << 8;
    __syncthreads();
    {
      float4 wA = *reinterpret_cast<const float4*>(wr1 + col);
      float4 wB = *reinterpret_cast<const float4*>(wr2 + col);
      *reinterpret_cast<float4*>(wbuf + (wid << 8) + (lane << 2)) = wA;
      *reinterpret_cast<float4*>(wbuf + (r2  << 8) + (lane << 2)) = wB;
    }
    float xr[16];
    if (tab) {
      const int tk = stokL[b];
      if (tk) {
        const float4* s4 = reinterpret_cast<const float4*>(
            tab + (size_t)tk * lenx + col + (tc << 4));
#pragma unroll
        for (int e = 0; e < 4; ++e) {
          float4 v = s4[e];
          xr[e*4] = v.x; xr[e*4+1] = v.y; xr[e*4+2] = v.z; xr[e*4+3] = v.w;
        }
      } else {
#pragma unroll
        for (int e = 0; e < 16; ++e) xr[e] = 0.f;
      }
    } else {
      const float* xp = xcoh + (size_t)b * lenx + col + (tc << 4);
#pragma unroll
      for (int e = 0; e < 8; ++e) {
        float2 v = ldc2(xp + 2*e); xr[2*e] = v.x; xr[2*e+1] = v.y;
      }
    }
    __syncthreads();
#pragma unroll
    for (int q = 0; q < 16; ++q) {
      const float4* w4 = reinterpret_cast<const float4*>(wbuf + (q << 8) + (tc << 4));
      float4 w0 = w4[0], w1 = w4[1], w2 = w4[2], w3 = w4[3];
      acc[q] += xr[0]*w0.x + xr[1]*w0.y + xr[2]*w0.z + xr[3]*w0.w
              + xr[4]*w1.x + xr[5]*w1.y + xr[6]*w1.z + xr[7]*w1.w
              + xr[8]*w2.x + xr[9]*w2.y + xr[10]*w2.z + xr[11]*w2.w
              + xr[12]*w3.x + xr[13]*w3.y + xr[14]*w3.z + xr[15]*w3.w;
    }
  }
}

// cross-slice reduce + cell + coherent h-store (red at SH+4096)
__device__ __forceinline__ void lstm_finish(
    const float* __restrict__ bias, int u0,
    const float* __restrict__ acc, float* __restrict__ cpriv,
    float* __restrict__ hdst, float* __restrict__ SH)
{
  const int tid = threadIdx.x;
  const int b = tid & 31, tc = tid >> 5;
  float* red = SH + 4096;
  __syncthreads();
#pragma unroll
  for (int q = 0; q < 16; ++q) red[(tc * 16 + q) * 33 + b] = acc[q];
  __syncthreads();
  if (tid < 128) {
    int bb = tid & 31, ul = tid >> 5;
    float g[4];
#pragma unroll
    for (int gg = 0; gg < 4; ++gg) {
      float s = bias[gg * HH + u0 + ul];
#pragma unroll
      for (int t2 = 0; t2 < 16; ++t2) s += red[(t2 * 16 + gg * 4 + ul) * 33 + bb];
      g[gg] = s;
    }
    float cn = sigf(g[1]) * cpriv[(bb << 2) + ul] + sigf(g[0]) * tanhf(g[2]);
    float hn = sigf(g[3]) * tanhf(cn);
    cpriv[(bb << 2) + ul] = cn;
    stc1(hdst + (size_t)bb * HH + u0 + ul, hn);
  }
  __syncthreads();
}

// ---------------------------------------------------------------------------
// FC tile, line-efficient + deep load pipeline. Wave = 32 j rows x 2 k-quads
// (r=lane&31, kq=lane>>5). Weight instr = 32 rows x 32B contiguous (lines
// completed by consecutive k-steps, no duplication). 8 waves = 2 j-halves x
// 4 b-groups of 8; acc[8]/lane. x staged in 256-k DOUBLE chunks (4 rounds,
// half the syncs); k-loop unroll 8 -> 8 weight loads in flight per wave.
// kq pair reduced via one shfl_xor(32).
// ---------------------------------------------------------------------------
__device__ __forceinline__ void fc_dot(const Par& p,
    const float* __restrict__ h0, int t0, int fcid,
    float* __restrict__ SH, bool do_am)
{
  const int tid = threadIdx.x;
  const int lane = tid & 63;
  const int w8 = tid >> 6;          // wave 0..7
  const int jt = w8 & 1;            // j half (+0 / +32)
  const int bq = w8 >> 1;           // 0..3 -> b group of 8
  const int r  = lane & 31;
  const int kq = lane >> 5;         // 0..1 -> k offset 0 / 4
  const int b0 = bq << 3;
  const int jrow = fcid * 64 + jt * 32 + r;
  const float* wp = p.fc_w + (size_t)jrow * HH + (kq << 2);
  float* SA = SH + 32 * XSTR;       // [32][66] argmax gather (8448..10560)

  float acc[8] = {0.f,0.f,0.f,0.f,0.f,0.f,0.f,0.f};

  for (int c = 0; c < 4; ++c) {     // 256-k double chunks
    __syncthreads();
    {   // stage x [32][256] -> SH[32][XSTR]
      const int sb = tid >> 4, cg = (tid & 15) << 4;
      const float* xp0 = h0 + (size_t)sb * HH + (c << 8) + cg;
      float* d0 = SH + sb * XSTR + cg;
#pragma unroll
      for (int e = 0; e < 4; ++e) {
        float2 va = ldc2(xp0 + 4*e), vb = ldc2(xp0 + 4*e + 2);
        *reinterpret_cast<float4*>(d0 + 4*e) = make_float4(va.x, va.y, vb.x, vb.y);
      }
    }
    __syncthreads();
    const float* wc = wp + (c << 8);
#pragma unroll 8
    for (int k0 = 0; k0 < 256; k0 += 8) {
      float4 w = *reinterpret_cast<const float4*>(wc + k0);
      const int xo = k0 + (kq << 2);
#pragma unroll
      for (int b = 0; b < 8; ++b) {
        float4 x4 = *reinterpret_cast<const float4*>(SH + (b0 + b) * XSTR + xo);
        acc[b] += w.x*x4.x + w.y*x4.y + w.z*x4.z + w.w*x4.w;
      }
    }
  }
  // reduce the kq pair in-register (lane bit 5)
#pragma unroll
  for (int e = 0; e < 8; ++e) acc[e] += __shfl_xor(acc[e], 32, 64);
  if (kq == 0) {
    const float wb = p.fc_b[jrow];
    const int jloc = jt * 32 + r;
#pragma unroll
    for (int b = 0; b < 8; ++b) {
      float v0 = acc[b] + wb;
      p.out[(size_t)(b0 + b) * TT * VV + (size_t)t0 * VV + jrow] = v0;
      if (do_am) SA[(b0 + b) * 66 + jloc] = v0;
    }
  }
  __syncthreads();
  if (do_am && tid < 32) {          // first-max over this tile's 64 j
    float bv = -FLTMAX; int bi = 0;
    const int jb = fcid * 64;
    for (int jj = 0; jj < 64; ++jj) {
      float v = SA[tid * 66 + jj];
      if (v > bv) { bv = v; bi = jb + jj; }
    }
    stc2((float*)&p.cand[fcid * 32 + tid], bv, __int_as_float(bi));
  }
  __syncthreads();
}

// AMred: block b (0..31) reduces 500 candidates -> p.tok[b] (argmax steps only)
__device__ __forceinline__ void amred(const Par& p, float* SH)
{
  const int tid = threadIdx.x;
  const int b = blockIdx.x;
  float bv = -FLTMAX; int bi = 0x7fffffff;
  if (tid < NFC) {
    float2 cv = ldc2((const float*)&p.cand[tid * 32 + b]);
    bv = cv.x; bi = __float_as_int(cv.y);
  }
  float* sv = SH; int* si = (int*)(SH + 512);
  sv[tid] = bv; si[tid] = bi;
  __syncthreads();
  for (int s = 256; s > 0; s >>= 1) {
    if (tid < s) {
      float ov = sv[tid + s]; int oi = si[tid + s];
      if (ov > sv[tid] || (ov == sv[tid] && oi < si[tid])) { sv[tid] = ov; si[tid] = oi; }
    }
    __syncthreads();
  }
  if (tid == 0)
    __hip_atomic_store(p.tok + b, si[0], __ATOMIC_RELAXED, __HIP_MEMORY_SCOPE_AGENT);
}

// ---------------------------------------------------------------------------
__global__ __launch_bounds__(BLK, 4) void mega(Par p) {
  __shared__ __attribute__((aligned(16))) float SH[12544];  // 50.2KB -> 2 blocks/CU
  __shared__ int stok[32];

  const int tid = threadIdx.x;
  const int bid = blockIdx.x;
  const int gid = bid * BLK + tid;
  int gen = 0;

  // ---- init
  for (int i = gid * 2; i < 2 * BB * HH; i += GRID * BLK * 2)
    stc2(p.hA0 + i, 0.f, 0.f);                       // hA0,hA1 contiguous
  for (int i = gid * 2; i < 2 * BB * HH; i += GRID * BLK * 2)
    stc2(p.hBall + 62 * BB * HH + i, 0.f, 0.f);      // hB slots 62,63 (enc ping-pong)
  if (tid < 128) {
    if (bid < 256) p.cA[bid * 128 + tid] = 0.f;
    else           p.cB[(bid - 256) * 128 + tid] = 0.f;
  }
  for (long g2 = gid; g2 < (long)BB * VV; g2 += (long)GRID * BLK) {
    int b = (int)(g2 / VV), v = (int)(g2 - (long)b * VV);
    __builtin_nontemporal_store(0.f, p.out + (size_t)b * TT * VV + v);
  }
  gbar(p.arr, p.gen, ++gen);

  // ---- encoder: L0(tt) on blocks 0..255 || L1(tt-1) on 256..511
  for (int tt = 0; tt <= SS; ++tt) {
    const int par = tt & 1;
    float* hA_w = par ? p.hA1 : p.hA0;
    float* hA_r = par ? p.hA0 : p.hA1;
    if (bid < 256) {
      if (tt < SS) {
        if (tid < 32) stok[tid] = p.src[tid * SS + tt];
        __syncthreads();
        const int u0 = bid * 4;
        float acc[16] = {0.f};
        lstm_accum(p.enc_embed, stok, nullptr, EE, p.enc_wih0, u0, acc, SH);
        lstm_accum(nullptr, nullptr, hA_r, HH, p.enc_whh0, u0, acc, SH);
        lstm_finish(p.enc_b0, u0, acc, p.cA + bid * 128, hA_w, SH);
      }
    } else {
      if (tt >= 1) {
        const int te = tt - 1;
        float* hB_w = p.hBall + (size_t)((te & 1) ? 63 : 62) * BB * HH;
        float* hB_r = p.hBall + (size_t)((te & 1) ? 62 : 63) * BB * HH;
        const int u0 = (bid - 256) * 4;
        float acc[16] = {0.f};
        lstm_accum(nullptr, nullptr, hA_r, HH, p.enc_wih1, u0, acc, SH);
        lstm_accum(nullptr, nullptr, hB_r, HH, p.enc_whh1, u0, acc, SH);
        lstm_finish(p.enc_b1, u0, acc, p.cB + (bid - 256) * 128, hB_w, SH);
      }
    }
    gbar(p.arr, p.gen, ++gen);
  }

  // ---- decoder: per step  [amred?] -> {L0||L1h} -> {L1x} -> {FC(t=k+1)}
  for (int k = 0; k < TT - 1; ++k) {
    const int par = k & 1;
    float* hA_r = par ? p.hA0 : p.hA1;    // k=0 -> hA1 (enc final)
    float* hA_w = par ? p.hA1 : p.hA0;
    float* hB_r = p.hBall + (size_t)((k + 63) & 63) * BB * HH;  // k=0 -> slot63
    float* hB_w = p.hBall + (size_t)k * BB * HH;
    const bool teach = (k == 0) || (p.tmask[k] > 0);

    if (!teach) {
      // cand for t=k was produced by the FC phase at the end of step k-1
      if (bid < 32) amred(p, SH);
      gbar(p.arr, p.gen, ++gen);
    }
    // L0 || L1h
    {
      float accB[16];
      if (bid < 256) {
        if (tid < 32) stok[tid] = teach ? p.tgt[tid * TT + k] : ldci(p.tok + tid);
        __syncthreads();
        const int u0 = bid * 4;
        float acc[16] = {0.f};
        lstm_accum(p.dec_embed, stok, nullptr, EE, p.dec_wih0, u0, acc, SH);
        lstm_accum(nullptr, nullptr, hA_r, HH, p.dec_whh0, u0, acc, SH);
        lstm_finish(p.dec_b0, u0, acc, p.cA + bid * 128, hA_w, SH);
      } else {
#pragma unroll
        for (int q = 0; q < 16; ++q) accB[q] = 0.f;
        lstm_accum(nullptr, nullptr, hB_r, HH, p.dec_whh1, (bid - 256) * 4, accB, SH);
      }
      gbar(p.arr, p.gen, ++gen);
      // L1x + cell
      if (bid >= 256) {
        const int u0 = (bid - 256) * 4;
        lstm_accum(nullptr, nullptr, hA_w, HH, p.dec_wih1, u0, accB, SH);
        lstm_finish(p.dec_b1, u0, accB, p.cB + (bid - 256) * 128, hB_w, SH);
      }
      gbar(p.arr, p.gen, ++gen);
    }
    // FC for logits t=k+1 (from hB(k) just written). do_am iff step k+1
    // needs an argmax token (k+1 <= TT-2 and tmask[k+1] == 0).
    {
      const int nt_ = k + 1;
      const bool do_am = (nt_ <= TT - 2) && (p.tmask[nt_] <= 0);
      if (bid < NFC) fc_dot(p, hB_w, nt_, bid, SH, do_am);
      gbar(p.arr, p.gen, ++gen);
    }
  }
}

// ---------------------------------------------------------------------------
extern "C" void kernel_launch(void* const* d_in, const int* in_sizes, int n_in,
                              void* d_out, int out_size, void* d_ws, size_t ws_size,
                              hipStream_t stream) {
  Par p;
  p.src       = (const int*)d_in[0];
  p.tgt       = (const int*)d_in[1];
  p.tmask     = (const int*)d_in[2];
  p.enc_embed = (const float*)d_in[3];
  p.dec_embed = (const float*)d_in[4];
  p.enc_wih0  = (const float*)d_in[5];
  p.enc_whh0  = (const float*)d_in[6];
  p.enc_b0    = (const float*)d_in[7];
  p.enc_wih1  = (const float*)d_in[8];
  p.enc_whh1  = (const float*)d_in[9];
  p.enc_b1    = (const float*)d_in[10];
  p.dec_wih0  = (const float*)d_in[11];
  p.dec_whh0  = (const float*)d_in[12];
  p.dec_b0    = (const float*)d_in[13];
  p.dec_wih1  = (const float*)d_in[14];
  p.dec_whh1  = (const float*)d_in[15];
  p.dec_b1    = (const float*)d_in[16];
  p.fc_w      = (const float*)d_in[17];
  p.fc_b      = (const float*)d_in[18];
  p.out       = (float*)d_out;

  p.arr = (int*)d_ws;                            // 512 slots x 64B
  p.gen = (int*)((char*)d_ws + 32768);           // 16 slots x 64B
  p.tok = (int*)((char*)d_ws + 34048);           // 32 ints
  float* f = (float*)((char*)d_ws + 36864);
  p.hA0   = f; f += BB * HH;
  p.hA1   = f; f += BB * HH;
  p.hBall = f; f += (size_t)64 * BB * HH;        // 8MB history ring
  p.cA    = f; f += 256 * 128;
  p.cB    = f; f += 256 * 128;
  p.cand  = (float2*)f; f += NFC * 32 * 2;

  hipMemsetAsync(d_ws, 0, 36864, stream);
  mega<<<dim3(GRID), dim3(BLK), 0, stream>>>(p);
}

// Round 16
// 12592.671 us; speedup vs baseline: 1.0659x; 1.0659x over previous
//
#include <hip/hip_runtime.h>

#define BB 32
#define SS 64
#define TT 64
#define VV 32000
#define EE 512
#define HH 1024
#define GRID 512
#define BLK 512
#define NFC 500          // FC tiles of 64 j
#define ASTR 16          // barrier slot stride in ints (64B)
#define XSTR 132         // FC x-chunk row stride (128 + 4 pad)
#define FLTMAX 3.402823466e38f

typedef unsigned long long u64;

struct Par {
  const int *src, *tgt, *tmask;
  const float *enc_embed, *dec_embed;
  const float *enc_wih0, *enc_whh0, *enc_b0;
  const float *enc_wih1, *enc_whh1, *enc_b1;
  const float *dec_wih0, *dec_whh0, *dec_b0;
  const float *dec_wih1, *dec_whh1, *dec_b1;
  const float *fc_w, *fc_b;
  float *out;
  float *hA0, *hA1;               // layer-0 h double buffer (coherent)
  float *hBall;                   // 64 slots x [32][1024] h-history (coherent)
  float *cA, *cB;                 // block-private cell state
  float2 *cand;                   // [500][32]
  int *tok;                       // [32]
  int *arr; int *gen;
};

__device__ __forceinline__ float sigf(float x) { return 1.0f / (1.0f + expf(-x)); }

// ---- coherent agent-scope RELAXED access (no L2-invalidate fences) --------
__device__ __forceinline__ float2 ldc2(const float* p) {
  u64 v = __hip_atomic_load((const u64*)p, __ATOMIC_RELAXED, __HIP_MEMORY_SCOPE_AGENT);
  union { u64 u; float2 f; } c; c.u = v; return c.f;
}
__device__ __forceinline__ void stc2(float* p, float x, float y) {
  union { u64 u; float2 f; } c; c.f = make_float2(x, y);
  __hip_atomic_store((u64*)p, c.u, __ATOMIC_RELAXED, __HIP_MEMORY_SCOPE_AGENT);
}
__device__ __forceinline__ void stc1(float* p, float x) {
  __hip_atomic_store(p, x, __ATOMIC_RELAXED, __HIP_MEMORY_SCOPE_AGENT);
}
__device__ __forceinline__ int ldci(const int* p) {
  return __hip_atomic_load(p, __ATOMIC_RELAXED, __HIP_MEMORY_SCOPE_AGENT);
}

// ---------------------------------------------------------------------------
// Fence-free grid barrier: 64B-stride arrival slots, 16 replicated gen lines,
// exponential-backoff polling. REQUIRES all 512 blocks co-resident.
// ---------------------------------------------------------------------------
__device__ __forceinline__ void gbar(int* arr, int* gen, int target) {
  __syncthreads();
  asm volatile("s_waitcnt vmcnt(0)" ::: "memory");
  if (blockIdx.x == 0) {
    if (threadIdx.x < 64) {
      const int s = threadIdx.x;
      int spin = 0;
      for (;;) {
        bool ok = true;
#pragma unroll
        for (int o = 0; o < GRID; o += 64) {
          int idx = s + o;
          int a = (idx == 0) ? target
              : __hip_atomic_load(arr + idx * ASTR, __ATOMIC_RELAXED, __HIP_MEMORY_SCOPE_AGENT);
          ok &= (a >= target);
        }
        if (__all(ok)) break;
        if (spin < 8) __builtin_amdgcn_s_sleep(1);
        else          __builtin_amdgcn_s_sleep(8);
        ++spin;
      }
    }
    __syncthreads();
    if (threadIdx.x < 16)
      __hip_atomic_store(gen + threadIdx.x * ASTR, target, __ATOMIC_RELAXED, __HIP_MEMORY_SCOPE_AGENT);
  } else {
    if (threadIdx.x == 0) {
      __hip_atomic_store(arr + blockIdx.x * ASTR, target, __ATOMIC_RELAXED, __HIP_MEMORY_SCOPE_AGENT);
      int spin = 0;
      while (__hip_atomic_load(gen + (blockIdx.x & 15) * ASTR, __ATOMIC_RELAXED, __HIP_MEMORY_SCOPE_AGENT) < target) {
        if (spin < 4)       __builtin_amdgcn_s_sleep(1);
        else if (spin < 16) __builtin_amdgcn_s_sleep(8);
        else                __builtin_amdgcn_s_sleep(32);
        ++spin;
      }
    }
    __syncthreads();
  }
  asm volatile("" ::: "memory");
}

// ---------------------------------------------------------------------------
// LSTM partial accumulate (u-tile 4 -> 16 gate rows, acc[16]); weights staged
// via LDS (coalesced 1KB/instr), read back as 2-way-broadcast b128 (free).
// Threads: b = tid&31, tc = tid>>5 (16 k-slices of 16 per 256-chunk).
// ---------------------------------------------------------------------------
__device__ __forceinline__ void lstm_accum(
    const float* __restrict__ tab, const int* __restrict__ stokL,
    const float* __restrict__ xcoh, int lenx,
    const float* __restrict__ W, int u0,
    float* __restrict__ acc, float* __restrict__ wbuf)
{
  const int tid = threadIdx.x;
  const int b = tid & 31, tc = tid >> 5;
  const int lane = tid & 63, wid = tid >> 6;
  const int r2 = wid + 8;
  const float* wr1 = W + (size_t)((wid >> 2) * HH + u0 + (wid & 3)) * lenx + (lane << 2);
  const float* wr2 = W + (size_t)((r2  >> 2) * HH + u0 + (r2  & 3)) * lenx + (lane << 2);
  const int ncx = lenx >> 8;
  for (int c = 0; c < ncx; ++c) {
    const int col = c << 8;
    __syncthreads();
    {
      float4 wA = *reinterpret_cast<const float4*>(wr1 + col);
      float4 wB = *reinterpret_cast<const float4*>(wr2 + col);
      *reinterpret_cast<float4*>(wbuf + (wid << 8) + (lane << 2)) = wA;
      *reinterpret_cast<float4*>(wbuf + (r2  << 8) + (lane << 2)) = wB;
    }
    float xr[16];
    if (tab) {
      const int tk = stokL[b];
      if (tk) {
        const float4* s4 = reinterpret_cast<const float4*>(
            tab + (size_t)tk * lenx + col + (tc << 4));
#pragma unroll
        for (int e = 0; e < 4; ++e) {
          float4 v = s4[e];
          xr[e*4] = v.x; xr[e*4+1] = v.y; xr[e*4+2] = v.z; xr[e*4+3] = v.w;
        }
      } else {
#pragma unroll
        for (int e = 0; e < 16; ++e) xr[e] = 0.f;
      }
    } else {
      const float* xp = xcoh + (size_t)b * lenx + col + (tc << 4);
#pragma unroll
      for (int e = 0; e < 8; ++e) {
        float2 v = ldc2(xp + 2*e); xr[2*e] = v.x; xr[2*e+1] = v.y;
      }
    }
    __syncthreads();
#pragma unroll
    for (int q = 0; q < 16; ++q) {
      const float4* w4 = reinterpret_cast<const float4*>(wbuf + (q << 8) + (tc << 4));
      float4 w0 = w4[0], w1 = w4[1], w2 = w4[2], w3 = w4[3];
      acc[q] += xr[0]*w0.x + xr[1]*w0.y + xr[2]*w0.z + xr[3]*w0.w
              + xr[4]*w1.x + xr[5]*w1.y + xr[6]*w1.z + xr[7]*w1.w
              + xr[8]*w2.x + xr[9]*w2.y + xr[10]*w2.z + xr[11]*w2.w
              + xr[12]*w3.x + xr[13]*w3.y + xr[14]*w3.z + xr[15]*w3.w;
    }
  }
}

// cross-slice reduce + cell + coherent h-store (red at SH+4096)
__device__ __forceinline__ void lstm_finish(
    const float* __restrict__ bias, int u0,
    const float* __restrict__ acc, float* __restrict__ cpriv,
    float* __restrict__ hdst, float* __restrict__ SH)
{
  const int tid = threadIdx.x;
  const int b = tid & 31, tc = tid >> 5;
  float* red = SH + 4096;
  __syncthreads();
#pragma unroll
  for (int q = 0; q < 16; ++q) red[(tc * 16 + q) * 33 + b] = acc[q];
  __syncthreads();
  if (tid < 128) {
    int bb = tid & 31, ul = tid >> 5;
    float g[4];
#pragma unroll
    for (int gg = 0; gg < 4; ++gg) {
      float s = bias[gg * HH + u0 + ul];
#pragma unroll
      for (int t2 = 0; t2 < 16; ++t2) s += red[(t2 * 16 + gg * 4 + ul) * 33 + bb];
      g[gg] = s;
    }
    float cn = sigf(g[1]) * cpriv[(bb << 2) + ul] + sigf(g[0]) * tanhf(g[2]);
    float hn = sigf(g[3]) * tanhf(cn);
    cpriv[(bb << 2) + ul] = cn;
    stc1(hdst + (size_t)bb * HH + u0 + ul, hn);
  }
  __syncthreads();
}

// ---------------------------------------------------------------------------
// FC tile, LDS-issue-halved. Lane owns a j-PAIR (r, r+32): each x ds_read
// feeds 2 j-rows (8 ds_read : 64 FMA per iter, was 8:32). 8 waves = 4
// b-groups of 8 x 2 k-halves (kh); both kh chunks staged per round (double
// buffer) so all waves stay active. kq pair (lane>>5) reduced via shfl;
// kh partials merged through red[32][66] in LDS (reused for argmax).
// Weight instr = 32 distinct rows x 32B contiguous (line-efficient, r14).
// acc[16] flat, no j-loop -> no unroll-doubling spill (r13 lesson).
// ---------------------------------------------------------------------------
__device__ __forceinline__ void fc_dot(const Par& p,
    const float* __restrict__ h0, int t0, int fcid,
    float* __restrict__ SH, bool do_am)
{
  const int tid = threadIdx.x;
  const int lane = tid & 63;
  const int w8 = tid >> 6;          // wave 0..7
  const int bq = w8 & 3;            // b-group of 8
  const int kh = w8 >> 2;           // k half: 0 -> k<512, 1 -> k>=512
  const int r  = lane & 31;
  const int kq = lane >> 5;         // k offset 0 / 4
  const int b0 = bq << 3;
  const int jrow0 = fcid * 64 + r;
  const int jrow1 = jrow0 + 32;
  const float* wp0 = p.fc_w + (size_t)jrow0 * HH + (kh << 9) + (kq << 2);
  const float* wp1 = p.fc_w + (size_t)jrow1 * HH + (kh << 9) + (kq << 2);
  float* bufA = SH;                 // k-chunk c      (kh=0)
  float* bufB = SH + 32 * XSTR;     // k-chunk c+4    (kh=1)
  float* mybuf = kh ? bufB : bufA;
  float* red  = SH + 64 * XSTR;     // [32][66] kh-merge + argmax (8448..10560)

  float acc[16];
#pragma unroll
  for (int q = 0; q < 16; ++q) acc[q] = 0.f;

  for (int c = 0; c < 4; ++c) {
    __syncthreads();
    {   // stage chunk c -> bufA and chunk c+4 -> bufB ([32][128] each)
      const int sb = tid >> 4, cg = (tid & 15) << 3;
      const float* xa = h0 + (size_t)sb * HH + (c << 7) + cg;
      const float* xb = xa + 512;
      float* da = bufA + sb * XSTR + cg;
      float* db = bufB + sb * XSTR + cg;
      float2 a0 = ldc2(xa), a1 = ldc2(xa + 2), a2 = ldc2(xa + 4), a3 = ldc2(xa + 6);
      *reinterpret_cast<float4*>(da)     = make_float4(a0.x, a0.y, a1.x, a1.y);
      *reinterpret_cast<float4*>(da + 4) = make_float4(a2.x, a2.y, a3.x, a3.y);
      float2 c0 = ldc2(xb), c1 = ldc2(xb + 2), c2 = ldc2(xb + 4), c3 = ldc2(xb + 6);
      *reinterpret_cast<float4*>(db)     = make_float4(c0.x, c0.y, c1.x, c1.y);
      *reinterpret_cast<float4*>(db + 4) = make_float4(c2.x, c2.y, c3.x, c3.y);
    }
    __syncthreads();
    const float* wc0 = wp0 + (c << 7);
    const float* wc1 = wp1 + (c << 7);
#pragma unroll 4
    for (int k0 = 0; k0 < 128; k0 += 8) {
      float4 w0 = *reinterpret_cast<const float4*>(wc0 + k0);
      float4 w1 = *reinterpret_cast<const float4*>(wc1 + k0);
      const int xo = k0 + (kq << 2);
#pragma unroll
      for (int b = 0; b < 8; ++b) {
        float4 x4 = *reinterpret_cast<const float4*>(mybuf + (b0 + b) * XSTR + xo);
        acc[b]     += w0.x*x4.x + w0.y*x4.y + w0.z*x4.z + w0.w*x4.w;
        acc[8 + b] += w1.x*x4.x + w1.y*x4.y + w1.z*x4.z + w1.w*x4.w;
      }
    }
  }
  // reduce kq pair in-register (lane bit 5)
#pragma unroll
  for (int e = 0; e < 16; ++e) acc[e] += __shfl_xor(acc[e], 32, 64);
  if (kh == 1 && kq == 0) {         // publish upper-k partials
#pragma unroll
    for (int b = 0; b < 8; ++b) {
      red[(b0 + b) * 66 + r]      = acc[b];
      red[(b0 + b) * 66 + r + 32] = acc[8 + b];
    }
  }
  __syncthreads();
  if (kh == 0 && kq == 0) {         // merge, bias, store, stash for argmax
    const float wb0 = p.fc_b[jrow0], wb1 = p.fc_b[jrow1];
#pragma unroll
    for (int b = 0; b < 8; ++b) {
      float v0 = acc[b]     + red[(b0 + b) * 66 + r]      + wb0;
      float v1 = acc[8 + b] + red[(b0 + b) * 66 + r + 32] + wb1;
      p.out[(size_t)(b0 + b) * TT * VV + (size_t)t0 * VV + jrow0] = v0;
      p.out[(size_t)(b0 + b) * TT * VV + (size_t)t0 * VV + jrow1] = v1;
      red[(b0 + b) * 66 + r]      = v0;
      red[(b0 + b) * 66 + r + 32] = v1;
    }
  }
  __syncthreads();
  if (do_am && tid < 32) {          // first-max over this tile's 64 j
    float bv = -FLTMAX; int bi = 0;
    const int jb = fcid * 64;
    for (int jj = 0; jj < 64; ++jj) {
      float v = red[tid * 66 + jj];
      if (v > bv) { bv = v; bi = jb + jj; }
    }
    stc2((float*)&p.cand[fcid * 32 + tid], bv, __int_as_float(bi));
  }
  __syncthreads();
}

// AMred: block b (0..31) reduces 500 candidates -> p.tok[b] (argmax steps only)
__device__ __forceinline__ void amred(const Par& p, float* SH)
{
  const int tid = threadIdx.x;
  const int b = blockIdx.x;
  float bv = -FLTMAX; int bi = 0x7fffffff;
  if (tid < NFC) {
    float2 cv = ldc2((const float*)&p.cand[tid * 32 + b]);
    bv = cv.x; bi = __float_as_int(cv.y);
  }
  float* sv = SH; int* si = (int*)(SH + 512);
  sv[tid] = bv; si[tid] = bi;
  __syncthreads();
  for (int s = 256; s > 0; s >>= 1) {
    if (tid < s) {
      float ov = sv[tid + s]; int oi = si[tid + s];
      if (ov > sv[tid] || (ov == sv[tid] && oi < si[tid])) { sv[tid] = ov; si[tid] = oi; }
    }
    __syncthreads();
  }
  if (tid == 0)
    __hip_atomic_store(p.tok + b, si[0], __ATOMIC_RELAXED, __HIP_MEMORY_SCOPE_AGENT);
}

// ---------------------------------------------------------------------------
__global__ __launch_bounds__(BLK, 4) void mega(Par p) {
  __shared__ __attribute__((aligned(16))) float SH[12544];  // 50.2KB
  __shared__ int stok[32];

  const int tid = threadIdx.x;
  const int bid = blockIdx.x;
  const int gid = bid * BLK + tid;
  int gen = 0;

  // ---- init
  for (int i = gid * 2; i < 2 * BB * HH; i += GRID * BLK * 2)
    stc2(p.hA0 + i, 0.f, 0.f);                       // hA0,hA1 contiguous
  for (int i = gid * 2; i < 2 * BB * HH; i += GRID * BLK * 2)
    stc2(p.hBall + 62 * BB * HH + i, 0.f, 0.f);      // hB slots 62,63 (enc ping-pong)
  if (tid < 128) {
    if (bid < 256) p.cA[bid * 128 + tid] = 0.f;
    else           p.cB[(bid - 256) * 128 + tid] = 0.f;
  }
  for (long g2 = gid; g2 < (long)BB * VV; g2 += (long)GRID * BLK) {
    int b = (int)(g2 / VV), v = (int)(g2 - (long)b * VV);
    __builtin_nontemporal_store(0.f, p.out + (size_t)b * TT * VV + v);
  }
  gbar(p.arr, p.gen, ++gen);

  // ---- encoder: L0(tt) on blocks 0..255 || L1(tt-1) on 256..511
  for (int tt = 0; tt <= SS; ++tt) {
    const int par = tt & 1;
    float* hA_w = par ? p.hA1 : p.hA0;
    float* hA_r = par ? p.hA0 : p.hA1;
    if (bid < 256) {
      if (tt < SS) {
        if (tid < 32) stok[tid] = p.src[tid * SS + tt];
        __syncthreads();
        const int u0 = bid * 4;
        float acc[16] = {0.f};
        lstm_accum(p.enc_embed, stok, nullptr, EE, p.enc_wih0, u0, acc, SH);
        lstm_accum(nullptr, nullptr, hA_r, HH, p.enc_whh0, u0, acc, SH);
        lstm_finish(p.enc_b0, u0, acc, p.cA + bid * 128, hA_w, SH);
      }
    } else {
      if (tt >= 1) {
        const int te = tt - 1;
        float* hB_w = p.hBall + (size_t)((te & 1) ? 63 : 62) * BB * HH;
        float* hB_r = p.hBall + (size_t)((te & 1) ? 62 : 63) * BB * HH;
        const int u0 = (bid - 256) * 4;
        float acc[16] = {0.f};
        lstm_accum(nullptr, nullptr, hA_r, HH, p.enc_wih1, u0, acc, SH);
        lstm_accum(nullptr, nullptr, hB_r, HH, p.enc_whh1, u0, acc, SH);
        lstm_finish(p.enc_b1, u0, acc, p.cB + (bid - 256) * 128, hB_w, SH);
      }
    }
    gbar(p.arr, p.gen, ++gen);
  }

  // ---- decoder: per step  [amred?] -> {L0||L1h} -> {L1x} -> {FC(t=k+1)}
  for (int k = 0; k < TT - 1; ++k) {
    const int par = k & 1;
    float* hA_r = par ? p.hA0 : p.hA1;    // k=0 -> hA1 (enc final)
    float* hA_w = par ? p.hA1 : p.hA0;
    float* hB_r = p.hBall + (size_t)((k + 63) & 63) * BB * HH;  // k=0 -> slot63
    float* hB_w = p.hBall + (size_t)k * BB * HH;
    const bool teach = (k == 0) || (p.tmask[k] > 0);

    if (!teach) {
      // cand for t=k was produced by the FC phase at the end of step k-1
      if (bid < 32) amred(p, SH);
      gbar(p.arr, p.gen, ++gen);
    }
    // L0 || L1h
    {
      float accB[16];
      if (bid < 256) {
        if (tid < 32) stok[tid] = teach ? p.tgt[tid * TT + k] : ldci(p.tok + tid);
        __syncthreads();
        const int u0 = bid * 4;
        float acc[16] = {0.f};
        lstm_accum(p.dec_embed, stok, nullptr, EE, p.dec_wih0, u0, acc, SH);
        lstm_accum(nullptr, nullptr, hA_r, HH, p.dec_whh0, u0, acc, SH);
        lstm_finish(p.dec_b0, u0, acc, p.cA + bid * 128, hA_w, SH);
      } else {
#pragma unroll
        for (int q = 0; q < 16; ++q) accB[q] = 0.f;
        lstm_accum(nullptr, nullptr, hB_r, HH, p.dec_whh1, (bid - 256) * 4, accB, SH);
      }
      gbar(p.arr, p.gen, ++gen);
      // L1x + cell
      if (bid >= 256) {
        const int u0 = (bid - 256) * 4;
        lstm_accum(nullptr, nullptr, hA_w, HH, p.dec_wih1, u0, accB, SH);
        lstm_finish(p.dec_b1, u0, accB, p.cB + (bid - 256) * 128, hB_w, SH);
      }
      gbar(p.arr, p.gen, ++gen);
    }
    // FC for logits t=k+1 (from hB(k) just written). do_am iff step k+1
    // needs an argmax token (k+1 <= TT-2 and tmask[k+1] == 0).
    {
      const int nt_ = k + 1;
      const bool do_am = (nt_ <= TT - 2) && (p.tmask[nt_] <= 0);
      if (bid < NFC) fc_dot(p, hB_w, nt_, bid, SH, do_am);
      gbar(p.arr, p.gen, ++gen);
    }
  }
}

// ---------------------------------------------------------------------------
extern "C" void kernel_launch(void* const* d_in, const int* in_sizes, int n_in,
                              void* d_out, int out_size, void* d_ws, size_t ws_size,
                              hipStream_t stream) {
  Par p;
  p.src       = (const int*)d_in[0];
  p.tgt       = (const int*)d_in[1];
  p.tmask     = (const int*)d_in[2];
  p.enc_embed = (const float*)d_in[3];
  p.dec_embed = (const float*)d_in[4];
  p.enc_wih0  = (const float*)d_in[5];
  p.enc_whh0  = (const float*)d_in[6];
  p.enc_b0    = (const float*)d_in[7];
  p.enc_wih1  = (const float*)d_in[8];
  p.enc_whh1  = (const float*)d_in[9];
  p.enc_b1    = (const float*)d_in[10];
  p.dec_wih0  = (const float*)d_in[11];
  p.dec_whh0  = (const float*)d_in[12];
  p.dec_b0    = (const float*)d_in[13];
  p.dec_wih1  = (const float*)d_in[14];
  p.dec_whh1  = (const float*)d_in[15];
  p.dec_b1    = (const float*)d_in[16];
  p.fc_w      = (const float*)d_in[17];
  p.fc_b      = (const float*)d_in[18];
  p.out       = (float*)d_out;

  p.arr = (int*)d_ws;                            // 512 slots x 64B
  p.gen = (int*)((char*)d_ws + 32768);           // 16 slots x 64B
  p.tok = (int*)((char*)d_ws + 34048);           // 32 ints
  float* f = (float*)((char*)d_ws + 36864);
  p.hA0   = f; f += BB * HH;
  p.hA1   = f; f += BB * HH;
  p.hBall = f; f += (size_t)64 * BB * HH;        // 8MB history ring
  p.cA    = f; f += 256 * 128;
  p.cB    = f; f += 256 * 128;
  p.cand  = (float2*)f; f += NFC * 32 * 2;

  hipMemsetAsync(d_ws, 0, 36864, stream);
  mega<<<dim3(GRID), dim3(BLK), 0, stream>>>(p);
}

// Round 17
// 11493.054 us; speedup vs baseline: 1.1679x; 1.0957x over previous
//
#include <hip/hip_runtime.h>

#define BB 32
#define SS 64
#define TT 64
#define VV 32000
#define EE 512
#define HH 1024
#define GRID 512
#define BLK 512
#define NFC 500          // FC tiles of 64 j
#define ASTR 16          // barrier slot stride in ints (64B)
#define XSTR 132         // FC x-chunk row stride (128 + 4 pad)
#define FLTMAX 3.402823466e38f

typedef unsigned long long u64;

struct Par {
  const int *src, *tgt, *tmask;
  const float *enc_embed, *dec_embed;
  const float *enc_wih0, *enc_whh0, *enc_b0;
  const float *enc_wih1, *enc_whh1, *enc_b1;
  const float *dec_wih0, *dec_whh0, *dec_b0;
  const float *dec_wih1, *dec_whh1, *dec_b1;
  const float *fc_w, *fc_b;
  float *out;
  float *hA0, *hA1;               // layer-0 h double buffer (coherent)
  float *hBall;                   // 64 slots x [32][1024] h-history (coherent)
  float *cA, *cB;                 // block-private cell state
  float2 *cand;                   // [500][32]
  int *tok;                       // [32]
  int *arr; int *gen;
};

__device__ __forceinline__ float sigf(float x) { return 1.0f / (1.0f + expf(-x)); }

// ---- coherent agent-scope RELAXED access (no L2-invalidate fences) --------
__device__ __forceinline__ float2 ldc2(const float* p) {
  u64 v = __hip_atomic_load((const u64*)p, __ATOMIC_RELAXED, __HIP_MEMORY_SCOPE_AGENT);
  union { u64 u; float2 f; } c; c.u = v; return c.f;
}
__device__ __forceinline__ void stc2(float* p, float x, float y) {
  union { u64 u; float2 f; } c; c.f = make_float2(x, y);
  __hip_atomic_store((u64*)p, c.u, __ATOMIC_RELAXED, __HIP_MEMORY_SCOPE_AGENT);
}
__device__ __forceinline__ void stc1(float* p, float x) {
  __hip_atomic_store(p, x, __ATOMIC_RELAXED, __HIP_MEMORY_SCOPE_AGENT);
}
__device__ __forceinline__ int ldci(const int* p) {
  return __hip_atomic_load(p, __ATOMIC_RELAXED, __HIP_MEMORY_SCOPE_AGENT);
}

// ---------------------------------------------------------------------------
// Fence-free grid barrier: 64B-stride arrival slots, 16 replicated gen lines,
// exponential-backoff polling. REQUIRES all 512 blocks co-resident.
// ---------------------------------------------------------------------------
__device__ __forceinline__ void gbar(int* arr, int* gen, int target) {
  __syncthreads();
  asm volatile("s_waitcnt vmcnt(0)" ::: "memory");
  if (blockIdx.x == 0) {
    if (threadIdx.x < 64) {
      const int s = threadIdx.x;
      int spin = 0;
      for (;;) {
        bool ok = true;
#pragma unroll
        for (int o = 0; o < GRID; o += 64) {
          int idx = s + o;
          int a = (idx == 0) ? target
              : __hip_atomic_load(arr + idx * ASTR, __ATOMIC_RELAXED, __HIP_MEMORY_SCOPE_AGENT);
          ok &= (a >= target);
        }
        if (__all(ok)) break;
        if (spin < 8) __builtin_amdgcn_s_sleep(1);
        else          __builtin_amdgcn_s_sleep(8);
        ++spin;
      }
    }
    __syncthreads();
    if (threadIdx.x < 16)
      __hip_atomic_store(gen + threadIdx.x * ASTR, target, __ATOMIC_RELAXED, __HIP_MEMORY_SCOPE_AGENT);
  } else {
    if (threadIdx.x == 0) {
      __hip_atomic_store(arr + blockIdx.x * ASTR, target, __ATOMIC_RELAXED, __HIP_MEMORY_SCOPE_AGENT);
      int spin = 0;
      while (__hip_atomic_load(gen + (blockIdx.x & 15) * ASTR, __ATOMIC_RELAXED, __HIP_MEMORY_SCOPE_AGENT) < target) {
        if (spin < 4)       __builtin_amdgcn_s_sleep(1);
        else if (spin < 16) __builtin_amdgcn_s_sleep(8);
        else                __builtin_amdgcn_s_sleep(32);
        ++spin;
      }
    }
    __syncthreads();
  }
  asm volatile("" ::: "memory");
}

// ---------------------------------------------------------------------------
// LSTM partial accumulate (u-tile 4 -> 16 gate rows, acc[16]); weights staged
// via LDS (coalesced 1KB/instr), read back as 2-way-broadcast b128 (free).
// Threads: b = tid&31, tc = tid>>5 (16 k-slices of 16 per 256-chunk).
// ---------------------------------------------------------------------------
__device__ __forceinline__ void lstm_accum(
    const float* __restrict__ tab, const int* __restrict__ stokL,
    const float* __restrict__ xcoh, int lenx,
    const float* __restrict__ W, int u0,
    float* __restrict__ acc, float* __restrict__ wbuf)
{
  const int tid = threadIdx.x;
  const int b = tid & 31, tc = tid >> 5;
  const int lane = tid & 63, wid = tid >> 6;
  const int r2 = wid + 8;
  const float* wr1 = W + (size_t)((wid >> 2) * HH + u0 + (wid & 3)) * lenx + (lane << 2);
  const float* wr2 = W + (size_t)((r2  >> 2) * HH + u0 + (r2  & 3)) * lenx + (lane << 2);
  const int ncx = lenx >> 8;
  for (int c = 0; c < ncx; ++c) {
    const int col = c << 8;
    __syncthreads();
    {
      float4 wA = *reinterpret_cast<const float4*>(wr1 + col);
      float4 wB = *reinterpret_cast<const float4*>(wr2 + col);
      *reinterpret_cast<float4*>(wbuf + (wid << 8) + (lane << 2)) = wA;
      *reinterpret_cast<float4*>(wbuf + (r2  << 8) + (lane << 2)) = wB;
    }
    float xr[16];
    if (tab) {
      const int tk = stokL[b];
      if (tk) {
        const float4* s4 = reinterpret_cast<const float4*>(
            tab + (size_t)tk * lenx + col + (tc << 4));
#pragma unroll
        for (int e = 0; e < 4; ++e) {
          float4 v = s4[e];
          xr[e*4] = v.x; xr[e*4+1] = v.y; xr[e*4+2] = v.z; xr[e*4+3] = v.w;
        }
      } else {
#pragma unroll
        for (int e = 0; e < 16; ++e) xr[e] = 0.f;
      }
    } else {
      const float* xp = xcoh + (size_t)b * lenx + col + (tc << 4);
#pragma unroll
      for (int e = 0; e < 8; ++e) {
        float2 v = ldc2(xp + 2*e); xr[2*e] = v.x; xr[2*e+1] = v.y;
      }
    }
    __syncthreads();
#pragma unroll
    for (int q = 0; q < 16; ++q) {
      const float4* w4 = reinterpret_cast<const float4*>(wbuf + (q << 8) + (tc << 4));
      float4 w0 = w4[0], w1 = w4[1], w2 = w4[2], w3 = w4[3];
      acc[q] += xr[0]*w0.x + xr[1]*w0.y + xr[2]*w0.z + xr[3]*w0.w
              + xr[4]*w1.x + xr[5]*w1.y + xr[6]*w1.z + xr[7]*w1.w
              + xr[8]*w2.x + xr[9]*w2.y + xr[10]*w2.z + xr[11]*w2.w
              + xr[12]*w3.x + xr[13]*w3.y + xr[14]*w3.z + xr[15]*w3.w;
    }
  }
}

// cross-slice reduce + cell + coherent h-store (red at SH+4096)
__device__ __forceinline__ void lstm_finish(
    const float* __restrict__ bias, int u0,
    const float* __restrict__ acc, float* __restrict__ cpriv,
    float* __restrict__ hdst, float* __restrict__ SH)
{
  const int tid = threadIdx.x;
  const int b = tid & 31, tc = tid >> 5;
  float* red = SH + 4096;
  __syncthreads();
#pragma unroll
  for (int q = 0; q < 16; ++q) red[(tc * 16 + q) * 33 + b] = acc[q];
  __syncthreads();
  if (tid < 128) {
    int bb = tid & 31, ul = tid >> 5;
    float g[4];
#pragma unroll
    for (int gg = 0; gg < 4; ++gg) {
      float s = bias[gg * HH + u0 + ul];
#pragma unroll
      for (int t2 = 0; t2 < 16; ++t2) s += red[(t2 * 16 + gg * 4 + ul) * 33 + bb];
      g[gg] = s;
    }
    float cn = sigf(g[1]) * cpriv[(bb << 2) + ul] + sigf(g[0]) * tanhf(g[2]);
    float hn = sigf(g[3]) * tanhf(cn);
    cpriv[(bb << 2) + ul] = cn;
    stc1(hdst + (size_t)bb * HH + u0 + ul, hn);
  }
  __syncthreads();
}

// ---------------------------------------------------------------------------
// FC tile, line-efficient (r14 pattern) x NT time-steps (weights reused in
// REGISTERS across t). Wave = 32 j rows x 2 k-quads (r=lane&31, kq=lane>>5);
// weight instr = 32 distinct rows x 32B contiguous. 8 waves = 2 j-halves x
// 4 b-groups of 8; acc[8*NT] (<=16, spill-proof per r16). x for each t
// staged in [32][XSTR] LDS; one w-load feeds 8*NT FMA-quads.
// kq pair reduced via one shfl_xor(32). do_am reduces t0's tile argmax.
// ---------------------------------------------------------------------------
template<int NT>
__device__ __forceinline__ void fc_dot(const Par& p,
    const float* __restrict__ h0, const float* __restrict__ h1,
    int t0, int t1, int fcid, float* __restrict__ SH, bool do_am)
{
  const int tid = threadIdx.x;
  const int lane = tid & 63;
  const int w8 = tid >> 6;          // wave 0..7
  const int jt = w8 & 1;            // j half (+0 / +32)
  const int bq = w8 >> 1;           // 0..3 -> b group of 8
  const int r  = lane & 31;
  const int kq = lane >> 5;         // 0..1 -> k offset 0 / 4
  const int b0 = bq << 3;
  const int jrow = fcid * 64 + jt * 32 + r;
  const float* wp = p.fc_w + (size_t)jrow * HH + (kq << 2);
  float* bufA = SH;                 // x chunk for t0
  float* bufB = SH + 32 * XSTR;     // x chunk for t1 (NT==2)
  float* SA   = SH + 64 * XSTR;     // [32][66] argmax gather (8448..10560)

  float acc[8 * NT];
#pragma unroll
  for (int q = 0; q < 8 * NT; ++q) acc[q] = 0.f;

  for (int c = 0; c < 8; ++c) {
    __syncthreads();
    {   // stage x chunk(s) [32][128] -> [32][XSTR]
      const int sb = tid >> 4, cg = (tid & 15) << 3;
      const float* xp0 = h0 + (size_t)sb * HH + (c << 7) + cg;
      float* d0 = bufA + sb * XSTR + cg;
      float2 v0 = ldc2(xp0),     v1 = ldc2(xp0 + 2);
      float2 v2 = ldc2(xp0 + 4), v3 = ldc2(xp0 + 6);
      *reinterpret_cast<float4*>(d0)     = make_float4(v0.x, v0.y, v1.x, v1.y);
      *reinterpret_cast<float4*>(d0 + 4) = make_float4(v2.x, v2.y, v3.x, v3.y);
      if constexpr (NT == 2) {
        const float* xp1 = h1 + (size_t)sb * HH + (c << 7) + cg;
        float* d1 = bufB + sb * XSTR + cg;
        float2 u0v = ldc2(xp1),     u1v = ldc2(xp1 + 2);
        float2 u2v = ldc2(xp1 + 4), u3v = ldc2(xp1 + 6);
        *reinterpret_cast<float4*>(d1)     = make_float4(u0v.x, u0v.y, u1v.x, u1v.y);
        *reinterpret_cast<float4*>(d1 + 4) = make_float4(u2v.x, u2v.y, u3v.x, u3v.y);
      }
    }
    __syncthreads();
    const float* wc = wp + (c << 7);
#pragma unroll 4
    for (int k0 = 0; k0 < 128; k0 += 8) {
      float4 w = *reinterpret_cast<const float4*>(wc + k0);
      const int xo = k0 + (kq << 2);
#pragma unroll
      for (int b = 0; b < 8; ++b) {
        float4 x4 = *reinterpret_cast<const float4*>(bufA + (b0 + b) * XSTR + xo);
        acc[b] += w.x*x4.x + w.y*x4.y + w.z*x4.z + w.w*x4.w;
        if constexpr (NT == 2) {
          float4 y4 = *reinterpret_cast<const float4*>(bufB + (b0 + b) * XSTR + xo);
          acc[8 + b] += w.x*y4.x + w.y*y4.y + w.z*y4.z + w.w*y4.w;
        }
      }
    }
  }
  // reduce the kq pair in-register (lane bit 5)
#pragma unroll
  for (int e = 0; e < 8 * NT; ++e) acc[e] += __shfl_xor(acc[e], 32, 64);
  if (kq == 0) {
    const float wb = p.fc_b[jrow];
    const int jloc = jt * 32 + r;
#pragma unroll
    for (int b = 0; b < 8; ++b) {
      float v0 = acc[b] + wb;
      p.out[(size_t)(b0 + b) * TT * VV + (size_t)t0 * VV + jrow] = v0;
      if (do_am) SA[(b0 + b) * 66 + jloc] = v0;
      if constexpr (NT == 2)
        p.out[(size_t)(b0 + b) * TT * VV + (size_t)t1 * VV + jrow] = acc[8 + b] + wb;
    }
  }
  __syncthreads();
  if (do_am && tid < 32) {          // first-max over this tile's 64 j (t0)
    float bv = -FLTMAX; int bi = 0;
    const int jb = fcid * 64;
    for (int jj = 0; jj < 64; ++jj) {
      float v = SA[tid * 66 + jj];
      if (v > bv) { bv = v; bi = jb + jj; }
    }
    stc2((float*)&p.cand[fcid * 32 + tid], bv, __int_as_float(bi));
  }
  __syncthreads();
}

// AMred: block b (0..31) reduces 500 candidates -> p.tok[b] (argmax steps only)
__device__ __forceinline__ void amred(const Par& p, float* SH)
{
  const int tid = threadIdx.x;
  const int b = blockIdx.x;
  float bv = -FLTMAX; int bi = 0x7fffffff;
  if (tid < NFC) {
    float2 cv = ldc2((const float*)&p.cand[tid * 32 + b]);
    bv = cv.x; bi = __float_as_int(cv.y);
  }
  float* sv = SH; int* si = (int*)(SH + 512);
  sv[tid] = bv; si[tid] = bi;
  __syncthreads();
  for (int s = 256; s > 0; s >>= 1) {
    if (tid < s) {
      float ov = sv[tid + s]; int oi = si[tid + s];
      if (ov > sv[tid] || (ov == sv[tid] && oi < si[tid])) { sv[tid] = ov; si[tid] = oi; }
    }
    __syncthreads();
  }
  if (tid == 0)
    __hip_atomic_store(p.tok + b, si[0], __ATOMIC_RELAXED, __HIP_MEMORY_SCOPE_AGENT);
}

// ---------------------------------------------------------------------------
__global__ __launch_bounds__(BLK, 4) void mega(Par p) {
  __shared__ __attribute__((aligned(16))) float SH[12544];  // 50.2KB -> 2 blocks/CU
  __shared__ int stok[32];

  const int tid = threadIdx.x;
  const int bid = blockIdx.x;
  const int gid = bid * BLK + tid;
  int gen = 0;

  // ---- init
  for (int i = gid * 2; i < 2 * BB * HH; i += GRID * BLK * 2)
    stc2(p.hA0 + i, 0.f, 0.f);                       // hA0,hA1 contiguous
  for (int i = gid * 2; i < 2 * BB * HH; i += GRID * BLK * 2)
    stc2(p.hBall + 62 * BB * HH + i, 0.f, 0.f);      // hB slots 62,63 (enc ping-pong)
  if (tid < 128) {
    if (bid < 256) p.cA[bid * 128 + tid] = 0.f;
    else           p.cB[(bid - 256) * 128 + tid] = 0.f;
  }
  for (long g2 = gid; g2 < (long)BB * VV; g2 += (long)GRID * BLK) {
    int b = (int)(g2 / VV), v = (int)(g2 - (long)b * VV);
    __builtin_nontemporal_store(0.f, p.out + (size_t)b * TT * VV + v);
  }
  gbar(p.arr, p.gen, ++gen);

  // ---- encoder: L0(tt) on blocks 0..255 || L1(tt-1) on 256..511
  for (int tt = 0; tt <= SS; ++tt) {
    const int par = tt & 1;
    float* hA_w = par ? p.hA1 : p.hA0;
    float* hA_r = par ? p.hA0 : p.hA1;
    if (bid < 256) {
      if (tt < SS) {
        if (tid < 32) stok[tid] = p.src[tid * SS + tt];
        __syncthreads();
        const int u0 = bid * 4;
        float acc[16] = {0.f};
        lstm_accum(p.enc_embed, stok, nullptr, EE, p.enc_wih0, u0, acc, SH);
        lstm_accum(nullptr, nullptr, hA_r, HH, p.enc_whh0, u0, acc, SH);
        lstm_finish(p.enc_b0, u0, acc, p.cA + bid * 128, hA_w, SH);
      }
    } else {
      if (tt >= 1) {
        const int te = tt - 1;
        float* hB_w = p.hBall + (size_t)((te & 1) ? 63 : 62) * BB * HH;
        float* hB_r = p.hBall + (size_t)((te & 1) ? 62 : 63) * BB * HH;
        const int u0 = (bid - 256) * 4;
        float acc[16] = {0.f};
        lstm_accum(nullptr, nullptr, hA_r, HH, p.enc_wih1, u0, acc, SH);
        lstm_accum(nullptr, nullptr, hB_r, HH, p.enc_whh1, u0, acc, SH);
        lstm_finish(p.enc_b1, u0, acc, p.cB + (bid - 256) * 128, hB_w, SH);
      }
    }
    gbar(p.arr, p.gen, ++gen);
  }

  // ---- decoder; teacher-step FCs deferred and paired (argmax steps absorb one)
  int pend[4]; int npend = 0;
  for (int k = 0; k < TT - 1; ++k) {
    const int par = k & 1;
    float* hA_r = par ? p.hA0 : p.hA1;    // k=0 -> hA1 (enc final)
    float* hA_w = par ? p.hA1 : p.hA0;
    float* hB_r = p.hBall + (size_t)((k + 63) & 63) * BB * HH;  // k=0 -> slot63
    float* hB_w = p.hBall + (size_t)k * BB * HH;
    const bool teach = (k == 0) || (p.tmask[k] > 0);

    if (!teach) {
      // A: inline FC for logits t=k (argmax input); absorb one pending step
      if (npend > 0) {
        const int tq = pend[0];
        pend[0] = pend[1]; pend[1] = pend[2]; pend[2] = pend[3];
        --npend;
        if (bid < NFC)
          fc_dot<2>(p, hB_r, p.hBall + (size_t)(tq - 1) * BB * HH, k, tq, bid, SH, true);
      } else {
        if (bid < NFC)
          fc_dot<1>(p, hB_r, hB_r, k, k, bid, SH, true);
      }
      gbar(p.arr, p.gen, ++gen);
      // B: amred -> p.tok
      if (bid < 32) amred(p, SH);
      gbar(p.arr, p.gen, ++gen);
    }
    // L0 || L1h
    {
      float accB[16];
      if (bid < 256) {
        if (tid < 32) stok[tid] = teach ? p.tgt[tid * TT + k] : ldci(p.tok + tid);
        __syncthreads();
        const int u0 = bid * 4;
        float acc[16] = {0.f};
        lstm_accum(p.dec_embed, stok, nullptr, EE, p.dec_wih0, u0, acc, SH);
        lstm_accum(nullptr, nullptr, hA_r, HH, p.dec_whh0, u0, acc, SH);
        lstm_finish(p.dec_b0, u0, acc, p.cA + bid * 128, hA_w, SH);
      } else {
#pragma unroll
        for (int q = 0; q < 16; ++q) accB[q] = 0.f;
        lstm_accum(nullptr, nullptr, hB_r, HH, p.dec_whh1, (bid - 256) * 4, accB, SH);
      }
      gbar(p.arr, p.gen, ++gen);
      // L1x + cell
      if (bid >= 256) {
        const int u0 = (bid - 256) * 4;
        lstm_accum(nullptr, nullptr, hA_w, HH, p.dec_wih1, u0, accB, SH);
        lstm_finish(p.dec_b1, u0, accB, p.cB + (bid - 256) * 128, hB_w, SH);
      }
      gbar(p.arr, p.gen, ++gen);
    }
    // queue logits t=k+1 (from hB(k)): argmax step inlines; else defer.
    {
      const int nt_ = k + 1;
      const bool nt_inline = (nt_ <= TT - 2) && (p.tmask[nt_] <= 0);
      if (!nt_inline) { pend[npend] = nt_; ++npend; }
      if (npend == 4) {
        if (bid < NFC) {
          fc_dot<2>(p, p.hBall + (size_t)(pend[0]-1) * BB * HH,
                       p.hBall + (size_t)(pend[1]-1) * BB * HH,
                       pend[0], pend[1], bid, SH, false);
          fc_dot<2>(p, p.hBall + (size_t)(pend[2]-1) * BB * HH,
                       p.hBall + (size_t)(pend[3]-1) * BB * HH,
                       pend[2], pend[3], bid, SH, false);
        }
        npend = 0;
        gbar(p.arr, p.gen, ++gen);
      }
    }
  }
  // ---- final flush of remaining deferred logits (includes t=63)
  if (bid < NFC) {
    int i = 0;
    for (; i + 1 < npend; i += 2)
      fc_dot<2>(p, p.hBall + (size_t)(pend[i]-1) * BB * HH,
                   p.hBall + (size_t)(pend[i+1]-1) * BB * HH,
                   pend[i], pend[i+1], bid, SH, false);
    if (i < npend)
      fc_dot<1>(p, p.hBall + (size_t)(pend[i]-1) * BB * HH,
                   p.hBall + (size_t)(pend[i]-1) * BB * HH,
                   pend[i], pend[i], bid, SH, false);
  }
}

// ---------------------------------------------------------------------------
extern "C" void kernel_launch(void* const* d_in, const int* in_sizes, int n_in,
                              void* d_out, int out_size, void* d_ws, size_t ws_size,
                              hipStream_t stream) {
  Par p;
  p.src       = (const int*)d_in[0];
  p.tgt       = (const int*)d_in[1];
  p.tmask     = (const int*)d_in[2];
  p.enc_embed = (const float*)d_in[3];
  p.dec_embed = (const float*)d_in[4];
  p.enc_wih0  = (const float*)d_in[5];
  p.enc_whh0  = (const float*)d_in[6];
  p.enc_b0    = (const float*)d_in[7];
  p.enc_wih1  = (const float*)d_in[8];
  p.enc_whh1  = (const float*)d_in[9];
  p.enc_b1    = (const float*)d_in[10];
  p.dec_wih0  = (const float*)d_in[11];
  p.dec_whh0  = (const float*)d_in[12];
  p.dec_b0    = (const float*)d_in[13];
  p.dec_wih1  = (const float*)d_in[14];
  p.dec_whh1  = (const float*)d_in[15];
  p.dec_b1    = (const float*)d_in[16];
  p.fc_w      = (const float*)d_in[17];
  p.fc_b      = (const float*)d_in[18];
  p.out       = (float*)d_out;

  p.arr = (int*)d_ws;                            // 512 slots x 64B
  p.gen = (int*)((char*)d_ws + 32768);           // 16 slots x 64B
  p.tok = (int*)((char*)d_ws + 34048);           // 32 ints
  float* f = (float*)((char*)d_ws + 36864);
  p.hA0   = f; f += BB * HH;
  p.hA1   = f; f += BB * HH;
  p.hBall = f; f += (size_t)64 * BB * HH;        // 8MB history ring
  p.cA    = f; f += 256 * 128;
  p.cB    = f; f += 256 * 128;
  p.cand  = (float2*)f; f += NFC * 32 * 2;

  hipMemsetAsync(d_ws, 0, 36864, stream);
  mega<<<dim3(GRID), dim3(BLK), 0, stream>>>(p);
}